// Round 3
// baseline (83.092 us; speedup 1.0000x reference)
//
#include <hip/hip_runtime.h>
#include <hip/hip_cooperative_groups.h>
#include <math.h>

namespace cg = cooperative_groups;

#define H    1024
#define NH   16
#define HD   128
#define ID   2048                 // NH*HD
#define EPS  1e-6f
#define NBLK 256                  // one block per CU, all-resident
#define NTHR 256

__device__ __forceinline__ float waveReduceSum(float v) {
#pragma unroll
    for (int off = 32; off > 0; off >>= 1) v += __shfl_down(v, off, 64);
    return v;
}

// One cooperative kernel, 3 phases, 2 grid syncs.
// ws_qkv[6144] = q(2048) | k(2048) | v(2048); ws_zsig[2048] = z*sigmoid(z);
// ws_decay[16]; ws_ypart[16 heads][16 slices][128 e].
__global__ __launch_bounds__(NTHR) void fused_qwen_linattn(
    const float* __restrict__ x,
    const float* __restrict__ state_in,
    const float* __restrict__ conv,
    const float* __restrict__ Wqkv,
    const float* __restrict__ Wz,
    const float* __restrict__ Wa,
    const float* __restrict__ normw,
    const float* __restrict__ Wout,
    float* __restrict__ out,
    float* __restrict__ state_out,
    float* __restrict__ conv_out,
    float* __restrict__ ws_qkv,
    float* __restrict__ ws_zsig,
    float* __restrict__ ws_decay,
    float* __restrict__ ws_ypart)
{
    cg::grid_group grid = cg::this_grid();
    const int b    = blockIdx.x;
    const int t    = threadIdx.x;
    const int wave = t >> 6;
    const int lane = t & 63;

    __shared__ float smem[2048];   // phase2: part[8][32] float4 (first 1024 floats); phase3: gated[2048]

    // ================= Phase 1: qkv/z/a matvec + conv copy =================
    {
        const float4* x4 = (const float4*)x;
        float4 xv[4];
#pragma unroll
        for (int i = 0; i < 4; ++i) xv[i] = x4[lane + 64 * i];

        const int w = b * 4 + wave;           // 0..1023, 8 rows each -> rows 0..8191
#pragma unroll
        for (int rr = 0; rr < 8; ++rr) {
            const int r = w * 8 + rr;
            const float* row = (r < 3 * ID) ? (Wqkv + (size_t)r * H)
                                            : (Wz + (size_t)(r - 3 * ID) * H);
            const float4* row4 = (const float4*)row;
            float acc = 0.f;
#pragma unroll
            for (int i = 0; i < 4; ++i) {
                float4 wv = row4[lane + 64 * i];
                acc += wv.x * xv[i].x + wv.y * xv[i].y + wv.z * xv[i].z + wv.w * xv[i].w;
            }
            acc = waveReduceSum(acc);
            if (lane == 0) {
                if (r < 3 * ID) ws_qkv[r] = acc;
                else {
                    const float sig = 1.f / (1.f + expf(-acc));
                    ws_zsig[r - 3 * ID] = acc * sig;   // z * sigmoid(z)
                }
            }
        }

        // W_a rows (16) on wave 0 of blocks 0..15
        if (b < NH && wave == 0) {
            const float4* row4 = (const float4*)(Wa + (size_t)b * H);
            float acc = 0.f;
#pragma unroll
            for (int i = 0; i < 4; ++i) {
                float4 wv = row4[lane + 64 * i];
                acc += wv.x * xv[i].x + wv.y * xv[i].y + wv.z * xv[i].z + wv.w * xv[i].w;
            }
            acc = waveReduceSum(acc);
            if (lane == 0) ws_decay[b] = 1.f / (1.f + expf(-acc));
        }

        // conv passthrough: 4608 float4 on blocks 238..255
        if (b >= NBLK - 18) {
            const int i = (b - (NBLK - 18)) * NTHR + t;
            ((float4*)conv_out)[i] = ((const float4*)conv)[i];
        }
    }

    grid.sync();

    // ========== Phase 2: state update + partial readout (block = head x d-slice) ==========
    {
        const int h = b >> 4;        // head
        const int s = b & 15;        // d-slice (8 d-rows)
        const int dd = t >> 5;       // 0..7
        const int c  = t & 31;       // float4 column, e = 4c..4c+3
        const int d  = s * 8 + dd;

        const float decay = ws_decay[h];
        const float* q = ws_qkv + h * HD;
        const float* k = ws_qkv + ID + h * HD;
        const float4 vv = ((const float4*)(ws_qkv + 2 * ID + h * HD))[c];

        const float4* sin4 = (const float4*)(state_in  + (size_t)h * HD * HD);
        float4*       sout = (float4*)(state_out + (size_t)h * HD * HD);

        const float kd = k[d];
        const float qd = q[d];
        float4 sv = sin4[d * 32 + c];
        float4 sn;
        sn.x = sv.x * decay + kd * vv.x;
        sn.y = sv.y * decay + kd * vv.y;
        sn.z = sv.z * decay + kd * vv.z;
        sn.w = sv.w * decay + kd * vv.w;
        sout[d * 32 + c] = sn;

        float4* part = (float4*)smem;      // [8][32]
        float4 acc;
        acc.x = qd * sn.x; acc.y = qd * sn.y; acc.z = qd * sn.z; acc.w = qd * sn.w;
        part[dd * 32 + c] = acc;
        __syncthreads();

        if (t < HD) {
            float y = 0.f;
#pragma unroll
            for (int d2 = 0; d2 < 8; ++d2) y += smem[(d2 * 32 + (t >> 2)) * 4 + (t & 3)];
            ws_ypart[(h * 16 + s) * HD + t] = y;
        }
    }

    grid.sync();
    __syncthreads();   // smem reuse fence within block

    // ========== Phase 3: recompute gated[2048] per block, then 4 W_out rows ==========
    {
        // thread t handles 8 e's of head h = t>>4
        const int h  = t >> 4;
        const int eb = (t & 15) * 8;
        float y[8];
#pragma unroll
        for (int j = 0; j < 8; ++j) y[j] = 0.f;
        for (int s2 = 0; s2 < 16; ++s2) {
            const float4* yp = (const float4*)(ws_ypart + (h * 16 + s2) * HD + eb);
            float4 a0 = yp[0], a1 = yp[1];
            y[0] += a0.x; y[1] += a0.y; y[2] += a0.z; y[3] += a0.w;
            y[4] += a1.x; y[5] += a1.y; y[6] += a1.z; y[7] += a1.w;
        }
        float ss = 0.f;
#pragma unroll
        for (int j = 0; j < 8; ++j) ss += y[j] * y[j];
        // reduce over the 16 lanes of this head (lane groups align: 4 heads per wave)
        ss += __shfl_xor(ss, 1, 16);
        ss += __shfl_xor(ss, 2, 16);
        ss += __shfl_xor(ss, 4, 16);
        ss += __shfl_xor(ss, 8, 16);
        const float scale = rsqrtf(ss * (1.f / HD) + EPS);
#pragma unroll
        for (int j = 0; j < 8; ++j) {
            const int e = eb + j;
            smem[h * HD + e] = y[j] * scale * normw[e] * ws_zsig[h * HD + e];
        }
    }
    __syncthreads();
    {
        const int r = b * 4 + wave;          // 0..1023
        const float4* row4 = (const float4*)(Wout + (size_t)r * ID);
        const float4* g4   = (const float4*)smem;
        float acc = 0.f;
#pragma unroll
        for (int i = 0; i < 8; ++i) {
            float4 wv = row4[lane + 64 * i];
            float4 gv = g4[lane + 64 * i];
            acc += wv.x * gv.x + wv.y * gv.y + wv.z * gv.z + wv.w * gv.w;
        }
        acc = waveReduceSum(acc);
        if (lane == 0) out[r] = acc;
    }
}

extern "C" void kernel_launch(void* const* d_in, const int* in_sizes, int n_in,
                              void* d_out, int out_size, void* d_ws, size_t ws_size,
                              hipStream_t stream) {
    const float* x     = (const float*)d_in[0];
    const float* state = (const float*)d_in[1];
    const float* conv  = (const float*)d_in[2];
    const float* Wqkv  = (const float*)d_in[3];
    const float* Wz    = (const float*)d_in[4];
    const float* Wa    = (const float*)d_in[5];
    const float* normw = (const float*)d_in[6];
    const float* Wout  = (const float*)d_in[7];

    float* out       = (float*)d_out;                    // [1024]
    float* new_state = out + H;                          // [16*128*128]
    float* conv_out  = new_state + (size_t)NH * HD * HD; // [18432]

    float* ws       = (float*)d_ws;
    float* ws_qkv   = ws;               // 6144
    float* ws_zsig  = ws + 6144;        // 2048
    float* ws_decay = ws + 8192;        // 16
    float* ws_ypart = ws + 8208;        // 16*16*128 = 32768

    void* args[] = {
        (void*)&x, (void*)&state, (void*)&conv, (void*)&Wqkv, (void*)&Wz,
        (void*)&Wa, (void*)&normw, (void*)&Wout, (void*)&out, (void*)&new_state,
        (void*)&conv_out, (void*)&ws_qkv, (void*)&ws_zsig, (void*)&ws_decay,
        (void*)&ws_ypart
    };
    hipLaunchCooperativeKernel((void*)fused_qwen_linattn,
                               dim3(NBLK), dim3(NTHR), args, 0, stream);
}

// Round 4
// 18.842 us; speedup vs baseline: 4.4099x; 4.4099x over previous
//
#include <hip/hip_runtime.h>
#include <math.h>

#define H    1024
#define NH   16
#define HD   128
#define ID   2048                 // NH*HD
#define NROWS_A (3*ID + ID + NH)  // 6144 qkv + 2048 z + 16 a = 8208
#define MATVEC_BLOCKS (NROWS_A / 4)   // 2052
#define CONV_FLOATS (3 * ID * 3)      // 18432 floats = 4608 float4
#define CONV_BLOCKS (CONV_FLOATS / 4 / 256)  // 18
#define EPS 1e-6f

__device__ __forceinline__ float waveReduceSum(float v) {
#pragma unroll
    for (int off = 32; off > 0; off >>= 1) v += __shfl_down(v, off, 64);
    return v;
}

// Kernel 1: fused matvec of x against W_qkv (6144 rows), W_z (2048), W_a (16),
// plus conv_state passthrough copy in trailing blocks.
// One wave (64 lanes) per row; each lane reads 4x float4 (1024 floats/row).
// z rows store z*sigmoid(z) directly; a rows store sigmoid(a).
__global__ __launch_bounds__(256) void matvec_qkvza(
    const float* __restrict__ x,
    const float* __restrict__ Wqkv,
    const float* __restrict__ Wz,
    const float* __restrict__ Wa,
    const float* __restrict__ conv,
    float* __restrict__ conv_out,
    float* __restrict__ ws_qkv,    // [6144]
    float* __restrict__ ws_zsig,   // [2048] = z * sigmoid(z)
    float* __restrict__ ws_decay)  // [16] (sigmoid applied)
{
    if (blockIdx.x >= MATVEC_BLOCKS) {
        const int i = (blockIdx.x - MATVEC_BLOCKS) * 256 + threadIdx.x;
        ((float4*)conv_out)[i] = ((const float4*)conv)[i];
        return;
    }

    const int wave = threadIdx.x >> 6;
    const int lane = threadIdx.x & 63;
    const int r = blockIdx.x * 4 + wave;

    const float* row;
    if (r < 3 * ID)           row = Wqkv + (size_t)r * H;
    else if (r < 3 * ID + ID) row = Wz   + (size_t)(r - 3 * ID) * H;
    else                      row = Wa   + (size_t)(r - 3 * ID - ID) * H;

    const float4* row4 = (const float4*)row;
    const float4* x4   = (const float4*)x;

    float acc = 0.f;
#pragma unroll
    for (int t = 0; t < 4; ++t) {
        float4 w  = row4[lane + 64 * t];
        float4 xv = x4[lane + 64 * t];
        acc += w.x * xv.x + w.y * xv.y + w.z * xv.z + w.w * xv.w;
    }
    acc = waveReduceSum(acc);
    if (lane == 0) {
        if (r < 3 * ID) {
            ws_qkv[r] = acc;
        } else if (r < 3 * ID + ID) {
            const float sig = 1.f / (1.f + expf(-acc));
            ws_zsig[r - 3 * ID] = acc * sig;
        } else {
            ws_decay[r - 3 * ID - ID] = 1.f / (1.f + expf(-acc));
        }
    }
}

// Kernel 2: new_state = state*decay + k (outer) v, plus partial
// y[h,s,e] = sum_{d in slice s} q[d]*new_state[d,e].
// 256 blocks = 16 heads x 16 d-slices; 256 threads = 8 d x 32 float4-columns.
// One float4 of state per thread, fully coalesced.
__global__ __launch_bounds__(256) void state_update(
    const float* __restrict__ state_in,
    const float* __restrict__ ws_qkv,
    const float* __restrict__ ws_decay,
    float* __restrict__ state_out,
    float* __restrict__ ws_ypart)   // [NH][16][HD]
{
    const int h  = blockIdx.x >> 4;
    const int s  = blockIdx.x & 15;
    const int dd = threadIdx.x >> 5;   // 0..7
    const int c  = threadIdx.x & 31;   // float4 column
    const int d  = s * 8 + dd;

    const float decay = ws_decay[h];
    const float qd = ws_qkv[h * HD + d];
    const float kd = ws_qkv[ID + h * HD + d];
    const float4 vv = ((const float4*)(ws_qkv + 2 * ID + h * HD))[c];

    const float4* sin4 = (const float4*)(state_in  + (size_t)h * HD * HD);
    float4*       sout = (float4*)(state_out + (size_t)h * HD * HD);

    float4 sv = sin4[d * 32 + c];
    float4 sn;
    sn.x = sv.x * decay + kd * vv.x;
    sn.y = sv.y * decay + kd * vv.y;
    sn.z = sv.z * decay + kd * vv.z;
    sn.w = sv.w * decay + kd * vv.w;
    sout[d * 32 + c] = sn;

    __shared__ float part[8][HD];   // 4 KB
    part[dd][4 * c + 0] = qd * sn.x;
    part[dd][4 * c + 1] = qd * sn.y;
    part[dd][4 * c + 2] = qd * sn.z;
    part[dd][4 * c + 3] = qd * sn.w;
    __syncthreads();

    const int t = threadIdx.x;
    if (t < HD) {
        float y = 0.f;
#pragma unroll
        for (int d2 = 0; d2 < 8; ++d2) y += part[d2][t];
        ws_ypart[(h * 16 + s) * HD + t] = y;
    }
}

// Kernel 3: per block, recompute gated[2048] from ypart (RMSNorm + silu-gate),
// then 4 rows of W_out. 256 blocks x 256 threads.
__global__ __launch_bounds__(256) void gate_out(
    const float* __restrict__ ws_ypart,
    const float* __restrict__ ws_zsig,
    const float* __restrict__ normw,
    const float* __restrict__ Wout,
    float* __restrict__ out)
{
    __shared__ float gated[ID];   // 8 KB
    const int t = threadIdx.x;
    {
        // thread t handles 8 e's of head h = t>>4
        const int h  = t >> 4;
        const int eb = (t & 15) * 8;
        float y[8];
#pragma unroll
        for (int j = 0; j < 8; ++j) y[j] = 0.f;
#pragma unroll 4
        for (int s = 0; s < 16; ++s) {
            const float4* yp = (const float4*)(ws_ypart + (h * 16 + s) * HD + eb);
            float4 a0 = yp[0], a1 = yp[1];
            y[0] += a0.x; y[1] += a0.y; y[2] += a0.z; y[3] += a0.w;
            y[4] += a1.x; y[5] += a1.y; y[6] += a1.z; y[7] += a1.w;
        }
        float ss = 0.f;
#pragma unroll
        for (int j = 0; j < 8; ++j) ss += y[j] * y[j];
        // reduce across the 16 lanes sharing this head (heads align to 16-lane groups)
        ss += __shfl_xor(ss, 1, 16);
        ss += __shfl_xor(ss, 2, 16);
        ss += __shfl_xor(ss, 4, 16);
        ss += __shfl_xor(ss, 8, 16);
        const float scale = rsqrtf(ss * (1.f / HD) + EPS);
#pragma unroll
        for (int j = 0; j < 8; ++j) {
            const int e = eb + j;
            gated[h * HD + e] = y[j] * scale * normw[e] * ws_zsig[h * HD + e];
        }
    }
    __syncthreads();
    {
        const int wave = t >> 6;
        const int lane = t & 63;
        const int r = blockIdx.x * 4 + wave;   // 0..1023
        const float4* row4 = (const float4*)(Wout + (size_t)r * ID);
        const float4* g4   = (const float4*)gated;
        float acc = 0.f;
#pragma unroll
        for (int i = 0; i < 8; ++i) {
            float4 wv = row4[lane + 64 * i];
            float4 gv = g4[lane + 64 * i];
            acc += wv.x * gv.x + wv.y * gv.y + wv.z * gv.z + wv.w * gv.w;
        }
        acc = waveReduceSum(acc);
        if (lane == 0) out[r] = acc;
    }
}

extern "C" void kernel_launch(void* const* d_in, const int* in_sizes, int n_in,
                              void* d_out, int out_size, void* d_ws, size_t ws_size,
                              hipStream_t stream) {
    const float* x     = (const float*)d_in[0];
    const float* state = (const float*)d_in[1];
    const float* conv  = (const float*)d_in[2];
    const float* Wqkv  = (const float*)d_in[3];
    const float* Wz    = (const float*)d_in[4];
    const float* Wa    = (const float*)d_in[5];
    const float* normw = (const float*)d_in[6];
    const float* Wout  = (const float*)d_in[7];

    float* out       = (float*)d_out;                    // [1024]
    float* new_state = out + H;                          // [16*128*128]
    float* conv_out  = new_state + (size_t)NH * HD * HD; // [18432]

    float* ws       = (float*)d_ws;
    float* ws_qkv   = ws;               // 6144
    float* ws_zsig  = ws + 6144;        // 2048
    float* ws_decay = ws + 8192;        // 16
    float* ws_ypart = ws + 8208;        // 16*16*128 = 32768

    matvec_qkvza<<<MATVEC_BLOCKS + CONV_BLOCKS, 256, 0, stream>>>(
        x, Wqkv, Wz, Wa, conv, conv_out, ws_qkv, ws_zsig, ws_decay);
    state_update<<<NH * 16, 256, 0, stream>>>(
        state, ws_qkv, ws_decay, new_state, ws_ypart);
    gate_out<<<H / 4, 256, 0, stream>>>(
        ws_ypart, ws_zsig, normw, Wout, out);
}